// Round 3
// baseline (1048.180 us; speedup 1.0000x reference)
//
#include <hip/hip_runtime.h>

typedef unsigned short u16;
typedef __attribute__((ext_vector_type(4))) float f32x4;
typedef __attribute__((ext_vector_type(8))) short bf16x8;
typedef __attribute__((ext_vector_type(4))) unsigned short u16x4;
typedef __attribute__((ext_vector_type(8))) unsigned short u16x8;

#define BT 9600
#define VOCAB 24000
#define NCB 188   /* 24064/128 col blocks of logits GEMM */

__device__ __forceinline__ u16 f2b(float f){
  union { float f; unsigned u; } c; c.f = f;
  unsigned u = c.u;
  return (u16)((u + 0x7FFFu + ((u >> 16) & 1u)) >> 16);   // RNE fp32->bf16
}
__device__ __forceinline__ float b2f(u16 v){
  union { unsigned u; float f; } c; c.u = ((unsigned)v) << 16;
  return c.f;
}

#define GLD16(g, l) __builtin_amdgcn_global_load_lds( \
    (__attribute__((address_space(1))) void*)(g), \
    (__attribute__((address_space(3))) void*)(l), 16, 0, 0)

// ---------------------------------------------------------------------------
// Shared 128x128 bf16 MFMA GEMM core, 2-phase double-buffered with counted
// vmcnt(8) waits. A:[M,K] bf16 row-major, B:[N,K] bf16 row-major, K%64==0.
// 256 threads = 4 waves (2x2), wave = 64x64 out = 4x4 frags of 16x16x32.
// LDS XOR-swizzled at 16B granules (g ^= row&7) on BOTH global src + ds_read.
// As/Bs are [2][8192] u16 (64 KiB total).
// ---------------------------------------------------------------------------
__device__ __forceinline__ void gemm_core(
    const u16* __restrict__ A, const u16* __restrict__ B,
    int K, int brow, int bcol, u16* As, u16* Bs, f32x4 acc[4][4])
{
  const int tid  = threadIdx.x;
  const int w    = tid >> 6;
  const int lane = tid & 63;
  const int wm = w >> 1, wn = w & 1;

  const f32x4 fz = {0.f, 0.f, 0.f, 0.f};
  #pragma unroll
  for (int m = 0; m < 4; ++m)
    #pragma unroll
    for (int n = 0; n < 4; ++n) acc[m][n] = fz;

  const int nkt = K >> 6;

  auto stage = [&](int kt, int buf) {
    #pragma unroll
    for (int i = 0; i < 4; ++i) {
      int gl  = i * 256 + tid;             // 16B-granule linear index 0..1023
      int row = gl >> 3;                   // tile row 0..127
      int g   = (gl & 7) ^ (row & 7);      // pre-swizzled source granule
      const u16* ga = A + (size_t)(brow + row) * K + (kt << 6) + (g << 3);
      GLD16(ga, As + buf * 8192 + (size_t)(i * 256 + w * 64) * 8);
      const u16* gb = B + (size_t)(bcol + row) * K + (kt << 6) + (g << 3);
      GLD16(gb, Bs + buf * 8192 + (size_t)(i * 256 + w * 64) * 8);
    }
  };

  stage(0, 0);
  int cur = 0;
  for (int kt = 0; kt < nkt; ++kt) {
    if (kt + 1 < nkt) {
      stage(kt + 1, cur ^ 1);
      asm volatile("s_waitcnt vmcnt(8)" ::: "memory");   // only tile kt's loads
    } else {
      asm volatile("s_waitcnt vmcnt(0)" ::: "memory");
    }
    __builtin_amdgcn_s_barrier();
    asm volatile("" ::: "memory");
    const u16* Ab = As + cur * 8192;
    const u16* Bb = Bs + cur * 8192;
    #pragma unroll
    for (int kk = 0; kk < 2; ++kk) {
      bf16x8 af[4], bf[4];
      #pragma unroll
      for (int m = 0; m < 4; ++m) {
        int row = wm * 64 + m * 16 + (lane & 15);
        int g   = (kk * 4 + (lane >> 4)) ^ (row & 7);
        af[m] = *(const bf16x8*)(Ab + row * 64 + g * 8);
      }
      #pragma unroll
      for (int n = 0; n < 4; ++n) {
        int row = wn * 64 + n * 16 + (lane & 15);
        int g   = (kk * 4 + (lane >> 4)) ^ (row & 7);
        bf[n] = *(const bf16x8*)(Bb + row * 64 + g * 8);
      }
      #pragma unroll
      for (int m = 0; m < 4; ++m)
        #pragma unroll
        for (int n = 0; n < 4; ++n)
          acc[m][n] = __builtin_amdgcn_mfma_f32_16x16x32_bf16(af[m], bf[n], acc[m][n], 0, 0, 0);
    }
    asm volatile("" ::: "memory");
    __builtin_amdgcn_s_barrier();          // all ds_reads of buf[cur] done
    cur ^= 1;
  }
}

// ---------------------------------------------------------------------------
// prep bodies
// ---------------------------------------------------------------------------
__device__ __forceinline__ void prep_main_body(
    const float* __restrict__ dec, const float* __restrict__ ctx,
    u16* __restrict__ Xcat, int tid)
{
  if (tid >= 9600 * 500) return;
  int r = tid / 500, k8 = (tid % 500) * 8;
  const float* src = (k8 < 2000) ? dec + (size_t)r * 2000 + k8
                                 : ctx + (size_t)r * 2000 + (k8 - 2000);
  const float4* s4 = (const float4*)src;
  float4 v0 = s4[0], v1 = s4[1];
  u16x8 o;
  o[0] = f2b(v0.x); o[1] = f2b(v0.y); o[2] = f2b(v0.z); o[3] = f2b(v0.w);
  o[4] = f2b(v1.x); o[5] = f2b(v1.y); o[6] = f2b(v1.z); o[7] = f2b(v1.w);
  *(u16x8*)(Xcat + (size_t)r * 4608 + k8) = o;
}

__device__ __forceinline__ void prep_emb_body(
    const int* __restrict__ y, const float* __restrict__ etab,
    u16* __restrict__ Xcat, int tid)
{
  if (tid >= 9600 * 152) return;
  int r = tid / 152, u = tid % 152;
  u16* xr = Xcat + (size_t)r * 4608;
  if (u >= 150) {                                // zero pads
    int base = (u == 150) ? 4300 : 4604;
    u16x4 z; z[0] = 0; z[1] = 0; z[2] = 0; z[3] = 0;
    *(u16x4*)(xr + base) = z;
    return;
  }
  int t = r % 50;
  int side = u / 75, j4 = (u % 75) * 4;
  int tt = (side == 0) ? (t == 0 ? 1 : t - 1) : (t == 49 ? 48 : t + 1);
  int tok = y[r - t + tt];
  float4 v = *(const float4*)(etab + (size_t)tok * 300 + j4);
  u16x4 o; o[0] = f2b(v.x); o[1] = f2b(v.y); o[2] = f2b(v.z); o[3] = f2b(v.w);
  *(u16x4*)(xr + (side == 0 ? 4000 : 4304) + j4) = o;
}

__device__ __forceinline__ void wcat_body(
    const float* __restrict__ Sw, const float* __restrict__ C0w, const float* __restrict__ Vw,
    const float* __restrict__ Sb, const float* __restrict__ Vb, const float* __restrict__ C0b,
    u16* __restrict__ Wcat, float* __restrict__ biasc, int tid)
{
  if (tid >= 640 * 4608) return;
  int n = tid / 4608, k = tid % 4608;
  float v = 0.f;
  if (n < 600) {
    if (k < 2000)                  v = Sw[n * 2000 + k];
    else if (k < 4000)             v = C0w[n * 2000 + (k - 2000)];
    else if (k < 4300)             v = Vw[n * 600 + (k - 4000)];
    else if (k >= 4304 && k < 4604) v = Vw[n * 600 + 300 + (k - 4304)];
  }
  Wcat[tid] = f2b(v);
  if (k == 0) biasc[n] = (n < 600) ? (Sb[n] + Vb[n] + C0b[n]) : 0.f;
}

__device__ __forceinline__ void conv_body(
    const float* __restrict__ src, u16* __restrict__ dst,
    int srows, int scols, int drows, int dcols4, int tid)
{
  if (tid >= drows * dcols4) return;
  int r = tid / dcols4, c4 = (tid % dcols4) * 4;
  u16x4 o; o[0] = 0; o[1] = 0; o[2] = 0; o[3] = 0;
  if (r < srows && c4 < scols) {
    float4 v = *(const float4*)(src + (size_t)r * scols + c4);
    o[0] = f2b(v.x); o[1] = f2b(v.y); o[2] = f2b(v.z); o[3] = f2b(v.w);
  }
  *(u16x4*)(dst + (size_t)r * (dcols4 * 4) + c4) = o;
}

// One mega-prep kernel: block ranges
//   [0,18750)  prep_main   [18750,24450) prep_emb   [24450,35970) wcat
//   [35970,43490) conv W1  [43490,43610) conv W2    [43610,43770) conv wih0
//   [43770,43834) conv wih1
__global__ __launch_bounds__(256) void k_prep_all(
    const float* __restrict__ dec, const float* __restrict__ ctx,
    const int* __restrict__ y, const float* __restrict__ etab,
    const float* __restrict__ Sw, const float* __restrict__ C0w,
    const float* __restrict__ Vw, const float* __restrict__ Sb,
    const float* __restrict__ Vb, const float* __restrict__ C0b,
    const float* __restrict__ W1, const float* __restrict__ W2w,
    const float* __restrict__ wih0, const float* __restrict__ wih1,
    u16* __restrict__ Xcat, u16* __restrict__ Wcat, float* __restrict__ biasc,
    u16* __restrict__ W1b, u16* __restrict__ W2b,
    u16* __restrict__ wih0b, u16* __restrict__ wih1b)
{
  int bid = blockIdx.x, th = threadIdx.x;
  if (bid < 18750)      prep_main_body(dec, ctx, Xcat, bid * 256 + th);
  else if (bid < 24450) prep_emb_body(y, etab, Xcat, (bid - 18750) * 256 + th);
  else if (bid < 35970) wcat_body(Sw, C0w, Vw, Sb, Vb, C0b, Wcat, biasc, (bid - 24450) * 256 + th);
  else if (bid < 43490) conv_body(W1,   W1b,   24000, 300, 24064, 80, (bid - 35970) * 256 + th);
  else if (bid < 43610) conv_body(W2w,  W2b,   300,   300, 384,   80, (bid - 43490) * 256 + th);
  else if (bid < 43770) conv_body(wih0, wih0b, 400,   300, 512,   80, (bid - 43610) * 256 + th);
  else                  conv_body(wih1, wih1b, 400,   100, 512,   32, (bid - 43770) * 256 + th);
}

// ---------------------------------------------------------------------------
// GEMM kernels
// ---------------------------------------------------------------------------
__global__ __launch_bounds__(256) void k_gemm_tlong(
    const u16* __restrict__ Xcat, const u16* __restrict__ Wcat,
    const float* __restrict__ biasc, u16* __restrict__ tb)
{
  __shared__ u16 As[16384], Bs[16384];
  f32x4 acc[4][4];
  int brow = blockIdx.y * 128, bcol = blockIdx.x * 128;
  gemm_core(Xcat, Wcat, 4608, brow, bcol, As, Bs, acc);
  int lane = threadIdx.x & 63, w = threadIdx.x >> 6;
  int wm = w >> 1, wn = w & 1;
  #pragma unroll
  for (int m = 0; m < 4; ++m)
    #pragma unroll
    for (int n = 0; n < 4; ++n)
      #pragma unroll
      for (int r = 0; r < 4; ++r) {
        int row = brow + wm * 64 + m * 16 + ((lane >> 4) << 2) + r;
        int col = bcol + wn * 64 + n * 16 + (lane & 15);
        float v = acc[m][n][r] + biasc[col];
        float o = __shfl_xor(v, 1);
        float t = fmaxf(v, o);
        if ((lane & 1) == 0)
          tb[(size_t)row * 320 + (col >> 1)] = f2b(t);   // maxout pair
      }
}

__global__ __launch_bounds__(256) void k_gemm_a(
    const u16* __restrict__ tb, const u16* __restrict__ W2b,
    const float* __restrict__ W2bias, const float* __restrict__ W1,
    const int* __restrict__ y, u16* __restrict__ ab, u16* __restrict__ qb)
{
  __shared__ u16 As[16384], Bs[16384];
  f32x4 acc[4][4];
  int brow = blockIdx.y * 128, bcol = blockIdx.x * 128;
  gemm_core(tb, W2b, 320, brow, bcol, As, Bs, acc);
  int lane = threadIdx.x & 63, w = threadIdx.x >> 6;
  int wm = w >> 1, wn = w & 1;
  #pragma unroll
  for (int m = 0; m < 4; ++m)
    #pragma unroll
    for (int n = 0; n < 4; ++n)
      #pragma unroll
      for (int r = 0; r < 4; ++r) {
        int row = brow + wm * 64 + m * 16 + ((lane >> 4) << 2) + r;
        int col = bcol + wn * 64 + n * 16 + (lane & 15);
        if (col < 320) {
          float bias = (col < 300) ? W2bias[col] : 0.f;
          float a = acc[m][n][r] + bias;
          ab[(size_t)row * 320 + col] = f2b(a);
          float q = 0.f;
          if (col < 300) {
            int yv = y[row];
            q = a * W1[(size_t)yv * 300 + col];
          }
          qb[(size_t)row * 320 + col] = f2b(q);
        }
      }
}

// Chunked bf16 logits GEMM: writes bf16 logits to lb (chunk-local rows) with
// a coalesced LDS-repack store, plus per-(row,colblock) expf partials.
__global__ __launch_bounds__(256) void k_gemm_logits_bf16(
    const u16* __restrict__ ab, const u16* __restrict__ W1b,
    u16* __restrict__ lb, float* __restrict__ part, int rb0)
{
  __shared__ u16 smem[32768];                 // 64 KiB: GEMM dbuf, then repack
  __shared__ float rowsum[128][2];
  f32x4 acc[4][4];
  int brow = (rb0 + blockIdx.y) * 128, bcol = blockIdx.x * 128;
  gemm_core(ab, W1b, 320, brow, bcol, smem, smem + 16384, acc);
  int lane = threadIdx.x & 63, w = threadIdx.x >> 6;
  int wm = w >> 1, wn = w & 1;
  // after gemm_core's final barrier, LDS is free for repack
  #pragma unroll
  for (int m = 0; m < 4; ++m)
    #pragma unroll
    for (int r = 0; r < 4; ++r) {
      int lrow = wm * 64 + m * 16 + ((lane >> 4) << 2) + r;
      float es = 0.f;
      #pragma unroll
      for (int n = 0; n < 4; ++n) {
        int lcol = wn * 64 + n * 16 + (lane & 15);
        float v = acc[m][n][r];
        smem[lrow * 136 + lcol] = f2b(v);     // [128][136] u16, +8 pad
        if (bcol + lcol < VOCAB) es += __expf(v);
      }
      es += __shfl_xor(es, 1); es += __shfl_xor(es, 2);
      es += __shfl_xor(es, 4); es += __shfl_xor(es, 8);
      if ((lane & 15) == 0) rowsum[lrow][wn] = es;
    }
  __syncthreads();
  if (threadIdx.x < 128)
    part[(size_t)(brow + threadIdx.x) * NCB + blockIdx.x] =
        rowsum[threadIdx.x][0] + rowsum[threadIdx.x][1];
  // coalesced store: 2048 chunks of 8 u16 (16B), 8 per thread
  int lrow_base = blockIdx.y * 128;           // chunk-local
  #pragma unroll
  for (int j = 0; j < 8; ++j) {
    int ch   = j * 256 + threadIdx.x;
    int rowl = ch >> 4;
    int c16  = (ch & 15) << 3;
    u16x8 v = *(const u16x8*)(smem + rowl * 136 + c16);
    *(u16x8*)(lb + (size_t)(lrow_base + rowl) * 24064 + bcol + c16) = v;
  }
}

// fp32 fallback (non-chunked): logits straight to d_out + partials
__global__ __launch_bounds__(256) void k_gemm_logits_f32(
    const u16* __restrict__ ab, const u16* __restrict__ W1b,
    float* __restrict__ dout, float* __restrict__ part)
{
  __shared__ u16 As[16384], Bs[16384];
  __shared__ float rowsum[128][2];
  f32x4 acc[4][4];
  int brow = blockIdx.y * 128, bcol = blockIdx.x * 128;
  gemm_core(ab, W1b, 320, brow, bcol, As, Bs, acc);
  int lane = threadIdx.x & 63, w = threadIdx.x >> 6;
  int wm = w >> 1, wn = w & 1;
  #pragma unroll
  for (int m = 0; m < 4; ++m)
    #pragma unroll
    for (int r = 0; r < 4; ++r) {
      int lrow = wm * 64 + m * 16 + ((lane >> 4) << 2) + r;
      size_t grow = (size_t)(brow + lrow);
      float es = 0.f;
      #pragma unroll
      for (int n = 0; n < 4; ++n) {
        int col = bcol + wn * 64 + n * 16 + (lane & 15);
        float v = acc[m][n][r];
        if (col < VOCAB) {
          dout[grow * VOCAB + col] = v;
          es += __expf(v);
        }
      }
      es += __shfl_xor(es, 1); es += __shfl_xor(es, 2);
      es += __shfl_xor(es, 4); es += __shfl_xor(es, 8);
      if ((lane & 15) == 0) rowsum[lrow][wn] = es;
    }
  __syncthreads();
  if (threadIdx.x < 128)
    part[(size_t)(brow + threadIdx.x) * NCB + blockIdx.x] =
        rowsum[threadIdx.x][0] + rowsum[threadIdx.x][1];
}

__global__ __launch_bounds__(256) void k_gemm_proj(
    const u16* __restrict__ Ab, const u16* __restrict__ Bb, int K,
    const float* __restrict__ b1, const float* __restrict__ b2, float* __restrict__ out)
{
  __shared__ u16 As[16384], Bs[16384];
  f32x4 acc[4][4];
  int brow = blockIdx.y * 128, bcol = blockIdx.x * 128;
  gemm_core(Ab, Bb, K, brow, bcol, As, Bs, acc);
  int lane = threadIdx.x & 63, w = threadIdx.x >> 6;
  int wm = w >> 1, wn = w & 1;
  #pragma unroll
  for (int m = 0; m < 4; ++m)
    #pragma unroll
    for (int n = 0; n < 4; ++n)
      #pragma unroll
      for (int r = 0; r < 4; ++r) {
        int row = brow + wm * 64 + m * 16 + ((lane >> 4) << 2) + r;
        int col = bcol + wn * 64 + n * 16 + (lane & 15);
        if (col < 400)
          out[(size_t)row * 400 + col] = acc[m][n][r] + b1[col] + b2[col];
      }
}

// ---------------------------------------------------------------------------
// softmax denom reduce + fixup
// ---------------------------------------------------------------------------
__global__ __launch_bounds__(256) void k_rowlog(
    const float* __restrict__ part, float* __restrict__ logl, int r0)
{
  int row = r0 + blockIdx.x * 4 + (threadIdx.x >> 6);
  int l = threadIdx.x & 63;
  const float* p = part + (size_t)row * NCB;
  float s = p[l] + p[l + 64] + (l < 60 ? p[l + 128] : 0.f);
  s += __shfl_xor(s, 1);  s += __shfl_xor(s, 2);  s += __shfl_xor(s, 4);
  s += __shfl_xor(s, 8);  s += __shfl_xor(s, 16); s += __shfl_xor(s, 32);
  if (l == 0) logl[row] = logf(s);
}

__global__ __launch_bounds__(256) void k_fixup(
    float4* __restrict__ out4, const float* __restrict__ logl)
{
  size_t i = (size_t)blockIdx.x * blockDim.x + threadIdx.x;
  size_t stride = (size_t)gridDim.x * blockDim.x;
  const size_t total = (size_t)BT * (VOCAB / 4);
  for (; i < total; i += stride) {
    size_t row = i / (VOCAB / 4);
    float l = logl[row];
    float4 v = out4[i];
    v.x -= l; v.y -= l; v.z -= l; v.w -= l;
    out4[i] = v;
  }
}

// chunked: lb holds rows [r0, r0+nrows) at local indices
__global__ __launch_bounds__(256) void k_fixup_bf16(
    const u16* __restrict__ lb, const float* __restrict__ logl,
    float* __restrict__ out, int r0, int nrows)
{
  size_t i = (size_t)blockIdx.x * blockDim.x + threadIdx.x;
  size_t stride = (size_t)gridDim.x * blockDim.x;
  const size_t total = (size_t)nrows * (VOCAB / 8);
  for (; i < total; i += stride) {
    size_t rowl = i / (VOCAB / 8);
    int c8 = (int)(i % (VOCAB / 8)) * 8;
    size_t row = r0 + rowl;
    float l = logl[row];
    u16x8 v = *(const u16x8*)(lb + rowl * 24064 + c8);
    float4 o0, o1;
    o0.x = b2f(v[0]) - l; o0.y = b2f(v[1]) - l; o0.z = b2f(v[2]) - l; o0.w = b2f(v[3]) - l;
    o1.x = b2f(v[4]) - l; o1.y = b2f(v[5]) - l; o1.z = b2f(v[6]) - l; o1.w = b2f(v[7]) - l;
    float* op = out + row * VOCAB + c8;
    *(float4*)op = o0;
    *(float4*)(op + 4) = o1;
  }
}

// ---------------------------------------------------------------------------
// LSTM recurrences
// ---------------------------------------------------------------------------
__global__ __launch_bounds__(512) void k_lstm0(
    const float* __restrict__ xp0, const float* __restrict__ whh0, u16* __restrict__ h0b)
{
  int b = blockIdx.x, g = threadIdx.x;
  __shared__ float h[100];
  __shared__ float act[400];
  float wrow[100];
  if (g < 400) {
    const float4* wr = (const float4*)(whh0 + (size_t)g * 100);
    #pragma unroll
    for (int q = 0; q < 25; ++q) {
      float4 t = wr[q];
      wrow[4 * q] = t.x; wrow[4 * q + 1] = t.y; wrow[4 * q + 2] = t.z; wrow[4 * q + 3] = t.w;
    }
  }
  if (g < 100) h[g] = 0.f;
  float c = 0.f;
  __syncthreads();
  for (int t = 0; t < 50; ++t) {
    if (g < 400) {
      float s = xp0[(size_t)(b * 50 + t) * 400 + g];
      const float4* hv = (const float4*)h;
      #pragma unroll
      for (int q = 0; q < 25; ++q) {
        float4 hh = hv[q];
        s += wrow[4 * q] * hh.x + wrow[4 * q + 1] * hh.y
           + wrow[4 * q + 2] * hh.z + wrow[4 * q + 3] * hh.w;
      }
      act[g] = (g >= 200 && g < 300) ? tanhf(s) : 1.f / (1.f + __expf(-s));
    }
    __syncthreads();
    if (g < 100) {
      c = act[100 + g] * c + act[g] * act[200 + g];
      float hn = act[300 + g] * tanhf(c);
      h[g] = hn;
      h0b[(size_t)(b * 50 + t) * 128 + g] = f2b(hn);
    } else if (g < 128) {
      h0b[(size_t)(b * 50 + t) * 128 + g] = 0;
    }
    __syncthreads();
  }
}

__global__ __launch_bounds__(512) void k_lstm1(
    const float* __restrict__ xp1, const float* __restrict__ whh1,
    const int* __restrict__ y, const float* __restrict__ wqe,
    const float* __restrict__ wqeb, float* __restrict__ qout)
{
  int b = blockIdx.x, g = threadIdx.x;
  __shared__ float h[100];
  __shared__ float act[400];
  __shared__ float hsel[100];
  __shared__ int idx1;
  float wrow[100];
  if (g < 400) {
    const float4* wr = (const float4*)(whh1 + (size_t)g * 100);
    #pragma unroll
    for (int q = 0; q < 25; ++q) {
      float4 t = wr[q];
      wrow[4 * q] = t.x; wrow[4 * q + 1] = t.y; wrow[4 * q + 2] = t.z; wrow[4 * q + 3] = t.w;
    }
  }
  if (g == 0) {
    int ix = 49;
    for (int t = 0; t < 50; ++t) { if (y[b * 50 + t] == 0) { ix = t; break; } }
    idx1 = ix;
  }
  if (g < 100) { h[g] = 0.f; hsel[g] = 0.f; }
  float c = 0.f;
  __syncthreads();
  for (int t = 0; t < 50; ++t) {
    if (g < 400) {
      float s = xp1[(size_t)(b * 50 + t) * 400 + g];
      const float4* hv = (const float4*)h;
      #pragma unroll
      for (int q = 0; q < 25; ++q) {
        float4 hh = hv[q];
        s += wrow[4 * q] * hh.x + wrow[4 * q + 1] * hh.y
           + wrow[4 * q + 2] * hh.z + wrow[4 * q + 3] * hh.w;
      }
      act[g] = (g >= 200 && g < 300) ? tanhf(s) : 1.f / (1.f + __expf(-s));
    }
    __syncthreads();
    if (g < 100) {
      c = act[100 + g] * c + act[g] * act[200 + g];
      float hn = act[300 + g] * tanhf(c);
      h[g] = hn;
      if (t == idx1) hsel[g] = hn;
    }
    __syncthreads();
  }
  if (g == 0) {
    float s = wqeb[0];
    for (int j = 0; j < 100; ++j) s += hsel[j] * wqe[j];
    qout[b] = 1.f / (1.f + __expf(-s));
  }
}

// ---------------------------------------------------------------------------
extern "C" void kernel_launch(void* const* d_in, const int* in_sizes, int n_in,
                              void* d_out, int out_size, void* d_ws, size_t ws_size,
                              hipStream_t stream) {
  const float* dec  = (const float*)d_in[0];
  const int*   y    = (const int*)d_in[1];
  const float* ctx  = (const float*)d_in[2];
  const float* etab = (const float*)d_in[3];
  const float* W1   = (const float*)d_in[4];
  const float* Sw   = (const float*)d_in[5];
  const float* Sb   = (const float*)d_in[6];
  const float* Vw   = (const float*)d_in[7];
  const float* Vb   = (const float*)d_in[8];
  const float* C0w  = (const float*)d_in[9];
  const float* C0b  = (const float*)d_in[10];
  const float* W2w  = (const float*)d_in[11];
  const float* W2bias = (const float*)d_in[12];
  const float* wih0 = (const float*)d_in[13];
  const float* whh0 = (const float*)d_in[14];
  const float* bih0 = (const float*)d_in[15];
  const float* bhh0 = (const float*)d_in[16];
  const float* wih1 = (const float*)d_in[17];
  const float* whh1 = (const float*)d_in[18];
  const float* bih1 = (const float*)d_in[19];
  const float* bhh1 = (const float*)d_in[20];
  const float* wqe  = (const float*)d_in[21];
  const float* wqeb = (const float*)d_in[22];

  char* ws = (char*)d_ws;
  u16*   Xcat  = (u16*)(ws + 0);            // 9600x4608 bf16 = 88,473,600
  u16*   Wcat  = (u16*)(ws + 88473600);     // 640x4608 bf16  =  5,898,240
  float* biasc = (float*)(ws + 94371840);   // 640 f32
  u16*   tb    = (u16*)(ws + 94374400);     // 9600x320 bf16
  u16*   W2b   = (u16*)(ws + 100518400);    // 384x320 bf16
  u16*   ab    = (u16*)(ws + 100764160);    // 9600x320 bf16
  u16*   qb    = (u16*)(ws + 106908160);    // 9600x320 bf16
  u16*   W1b   = (u16*)(ws + 113052160);    // 24064x320 bf16
  float* part  = (float*)(ws + 128453120);  // 9600x188 f32
  float* logl  = (float*)(ws + 135672320);  // 9600 f32
  u16*   wih0b = (u16*)(ws + 135710720);    // 512x320 bf16
  float* xp0   = (float*)(ws + 136038400);  // 9600x400 f32
  u16*   h0b   = (u16*)(ws + 151398400);    // 9600x128 bf16
  u16*   wih1b = (u16*)(ws + 153856000);    // 512x128 bf16
  float* xp1   = (float*)(ws + 153987072);  // 9600x400 f32  (end 169,347,072)
  u16*   lb    = (u16*)(ws + 169347072);    // 3200x24064 bf16 = 154,009,600 (chunk buf)
  const size_t WS_NEED_BF16 = 169347072ull + 154009600ull;   // 323,356,672
  const bool use_bf16_logits = (ws_size >= WS_NEED_BF16);

  float* bout  = (float*)d_out;
  float* qeout = bout + (size_t)BT * VOCAB;

  k_prep_all<<<43834, 256, 0, stream>>>(dec, ctx, y, etab, Sw, C0w, Vw, Sb, Vb, C0b,
                                        W1, W2w, wih0, wih1,
                                        Xcat, Wcat, biasc, W1b, W2b, wih0b, wih1b);

  k_gemm_tlong<<<dim3(5, 75), 256, 0, stream>>>(Xcat, Wcat, biasc, tb);
  k_gemm_a<<<dim3(3, 75), 256, 0, stream>>>(tb, W2b, W2bias, W1, y, ab, qb);

  if (use_bf16_logits) {
    for (int c = 0; c < 3; ++c) {           // 3 chunks of 25 row-blocks (3200 rows)
      k_gemm_logits_bf16<<<dim3(NCB, 25), 256, 0, stream>>>(ab, W1b, lb, part, 25 * c);
      k_rowlog<<<800, 256, 0, stream>>>(part, logl, 3200 * c);
      k_fixup_bf16<<<2048, 256, 0, stream>>>(lb, logl, bout, 3200 * c, 3200);
    }
  } else {
    k_gemm_logits_f32<<<dim3(NCB, 75), 256, 0, stream>>>(ab, W1b, bout, part);
    k_rowlog<<<2400, 256, 0, stream>>>(part, logl, 0);
    k_fixup<<<4096, 256, 0, stream>>>((float4*)bout, logl);
  }

  k_gemm_proj<<<dim3(4, 75), 256, 0, stream>>>(qb, wih0b, 320, bih0, bhh0, xp0);
  k_lstm0<<<192, 512, 0, stream>>>(xp0, whh0, h0b);
  k_gemm_proj<<<dim3(4, 75), 256, 0, stream>>>(h0b, wih1b, 128, bih1, bhh1, xp1);
  k_lstm1<<<192, 512, 0, stream>>>(xp1, whh1, y, wqe, wqeb, qeout);
}

// Round 4
// 943.632 us; speedup vs baseline: 1.1108x; 1.1108x over previous
//
#include <hip/hip_runtime.h>

typedef unsigned short u16;
typedef __attribute__((ext_vector_type(4))) float f32x4;
typedef __attribute__((ext_vector_type(8))) short bf16x8;
typedef __attribute__((ext_vector_type(4))) unsigned short u16x4;
typedef __attribute__((ext_vector_type(8))) unsigned short u16x8;

#define BT 9600
#define VOCAB 24000
#define NCB 188   /* 24064/128 col blocks of logits GEMM */

__device__ __forceinline__ u16 f2b(float f){
  union { float f; unsigned u; } c; c.f = f;
  unsigned u = c.u;
  return (u16)((u + 0x7FFFu + ((u >> 16) & 1u)) >> 16);   // RNE fp32->bf16
}
__device__ __forceinline__ float b2f(u16 v){
  union { unsigned u; float f; } c; c.u = ((unsigned)v) << 16;
  return c.f;
}

#define GLD16(g, l) __builtin_amdgcn_global_load_lds( \
    (__attribute__((address_space(1))) void*)(g), \
    (__attribute__((address_space(3))) void*)(l), 16, 0, 0)

// ---------------------------------------------------------------------------
// Shared 128x128 bf16 MFMA GEMM core, 2-phase double-buffered, counted
// vmcnt(8). A:[M,K] bf16 row-major, B:[N,K] bf16 row-major, K%64==0.
// 256 threads = 4 waves (2x2). LDS XOR-swizzled at 16B granules both sides.
// ---------------------------------------------------------------------------
__device__ __forceinline__ void gemm_core(
    const u16* __restrict__ A, const u16* __restrict__ B,
    int K, int brow, int bcol, u16* As, u16* Bs, f32x4 acc[4][4])
{
  const int tid  = threadIdx.x & 255;
  const int w    = tid >> 6;
  const int lane = tid & 63;
  const int wm = w >> 1, wn = w & 1;

  const f32x4 fz = {0.f, 0.f, 0.f, 0.f};
  #pragma unroll
  for (int m = 0; m < 4; ++m)
    #pragma unroll
    for (int n = 0; n < 4; ++n) acc[m][n] = fz;

  const int nkt = K >> 6;

  auto stage = [&](int kt, int buf) {
    #pragma unroll
    for (int i = 0; i < 4; ++i) {
      int gl  = i * 256 + tid;             // 16B-granule linear index 0..1023
      int row = gl >> 3;                   // tile row 0..127
      int g   = (gl & 7) ^ (row & 7);      // pre-swizzled source granule
      const u16* ga = A + (size_t)(brow + row) * K + (kt << 6) + (g << 3);
      GLD16(ga, As + buf * 8192 + (size_t)(i * 256 + w * 64) * 8);
      const u16* gb = B + (size_t)(bcol + row) * K + (kt << 6) + (g << 3);
      GLD16(gb, Bs + buf * 8192 + (size_t)(i * 256 + w * 64) * 8);
    }
  };

  stage(0, 0);
  int cur = 0;
  for (int kt = 0; kt < nkt; ++kt) {
    if (kt + 1 < nkt) {
      stage(kt + 1, cur ^ 1);
      asm volatile("s_waitcnt vmcnt(8)" ::: "memory");   // only tile kt's loads
    } else {
      asm volatile("s_waitcnt vmcnt(0)" ::: "memory");
    }
    __builtin_amdgcn_s_barrier();
    asm volatile("" ::: "memory");
    const u16* Ab = As + cur * 8192;
    const u16* Bb = Bs + cur * 8192;
    #pragma unroll
    for (int kk = 0; kk < 2; ++kk) {
      bf16x8 af[4], bf[4];
      #pragma unroll
      for (int m = 0; m < 4; ++m) {
        int row = wm * 64 + m * 16 + (lane & 15);
        int g   = (kk * 4 + (lane >> 4)) ^ (row & 7);
        af[m] = *(const bf16x8*)(Ab + row * 64 + g * 8);
      }
      #pragma unroll
      for (int n = 0; n < 4; ++n) {
        int row = wn * 64 + n * 16 + (lane & 15);
        int g   = (kk * 4 + (lane >> 4)) ^ (row & 7);
        bf[n] = *(const bf16x8*)(Bb + row * 64 + g * 8);
      }
      #pragma unroll
      for (int m = 0; m < 4; ++m)
        #pragma unroll
        for (int n = 0; n < 4; ++n)
          acc[m][n] = __builtin_amdgcn_mfma_f32_16x16x32_bf16(af[m], bf[n], acc[m][n], 0, 0, 0);
    }
    asm volatile("" ::: "memory");
    __builtin_amdgcn_s_barrier();          // all ds_reads of buf[cur] done
    cur ^= 1;
  }
}

// proj epilogue body (shared): out[row][0..400) = acc + b1 + b2
__device__ __forceinline__ void proj_epilogue(
    f32x4 acc[4][4], int brow, int bcol,
    const float* __restrict__ b1, const float* __restrict__ b2,
    float* __restrict__ out)
{
  int tid = threadIdx.x & 255;
  int lane = tid & 63, w = tid >> 6;
  int wm = w >> 1, wn = w & 1;
  #pragma unroll
  for (int m = 0; m < 4; ++m)
    #pragma unroll
    for (int n = 0; n < 4; ++n)
      #pragma unroll
      for (int r = 0; r < 4; ++r) {
        int row = brow + wm * 64 + m * 16 + ((lane >> 4) << 2) + r;
        int col = bcol + wn * 64 + n * 16 + (lane & 15);
        if (col < 400)
          out[(size_t)row * 400 + col] = acc[m][n][r] + b1[col] + b2[col];
      }
}

// ---------------------------------------------------------------------------
// prep bodies
// ---------------------------------------------------------------------------
__device__ __forceinline__ void prep_main_body(
    const float* __restrict__ dec, const float* __restrict__ ctx,
    u16* __restrict__ Xcat, int tid)
{
  if (tid >= 9600 * 500) return;
  int r = tid / 500, k8 = (tid % 500) * 8;
  const float* src = (k8 < 2000) ? dec + (size_t)r * 2000 + k8
                                 : ctx + (size_t)r * 2000 + (k8 - 2000);
  const float4* s4 = (const float4*)src;
  float4 v0 = s4[0], v1 = s4[1];
  u16x8 o;
  o[0] = f2b(v0.x); o[1] = f2b(v0.y); o[2] = f2b(v0.z); o[3] = f2b(v0.w);
  o[4] = f2b(v1.x); o[5] = f2b(v1.y); o[6] = f2b(v1.z); o[7] = f2b(v1.w);
  *(u16x8*)(Xcat + (size_t)r * 4608 + k8) = o;
}

__device__ __forceinline__ void prep_emb_body(
    const int* __restrict__ y, const float* __restrict__ etab,
    u16* __restrict__ Xcat, int tid)
{
  if (tid >= 9600 * 152) return;
  int r = tid / 152, u = tid % 152;
  u16* xr = Xcat + (size_t)r * 4608;
  if (u >= 150) {
    int base = (u == 150) ? 4300 : 4604;
    u16x4 z; z[0] = 0; z[1] = 0; z[2] = 0; z[3] = 0;
    *(u16x4*)(xr + base) = z;
    return;
  }
  int t = r % 50;
  int side = u / 75, j4 = (u % 75) * 4;
  int tt = (side == 0) ? (t == 0 ? 1 : t - 1) : (t == 49 ? 48 : t + 1);
  int tok = y[r - t + tt];
  float4 v = *(const float4*)(etab + (size_t)tok * 300 + j4);
  u16x4 o; o[0] = f2b(v.x); o[1] = f2b(v.y); o[2] = f2b(v.z); o[3] = f2b(v.w);
  *(u16x4*)(xr + (side == 0 ? 4000 : 4304) + j4) = o;
}

__device__ __forceinline__ void wcat_body(
    const float* __restrict__ Sw, const float* __restrict__ C0w, const float* __restrict__ Vw,
    const float* __restrict__ Sb, const float* __restrict__ Vb, const float* __restrict__ C0b,
    u16* __restrict__ Wcat, float* __restrict__ biasc, int tid)
{
  if (tid >= 640 * 4608) return;
  int n = tid / 4608, k = tid % 4608;
  float v = 0.f;
  if (n < 600) {
    if (k < 2000)                  v = Sw[n * 2000 + k];
    else if (k < 4000)             v = C0w[n * 2000 + (k - 2000)];
    else if (k < 4300)             v = Vw[n * 600 + (k - 4000)];
    else if (k >= 4304 && k < 4604) v = Vw[n * 600 + 300 + (k - 4304)];
  }
  Wcat[tid] = f2b(v);
  if (k == 0) biasc[n] = (n < 600) ? (Sb[n] + Vb[n] + C0b[n]) : 0.f;
}

__device__ __forceinline__ void conv_body(
    const float* __restrict__ src, u16* __restrict__ dst,
    int srows, int scols, int drows, int dcols4, int tid)
{
  if (tid >= drows * dcols4) return;
  int r = tid / dcols4, c4 = (tid % dcols4) * 4;
  u16x4 o; o[0] = 0; o[1] = 0; o[2] = 0; o[3] = 0;
  if (r < srows && c4 < scols) {
    float4 v = *(const float4*)(src + (size_t)r * scols + c4);
    o[0] = f2b(v.x); o[1] = f2b(v.y); o[2] = f2b(v.z); o[3] = f2b(v.w);
  }
  *(u16x4*)(dst + (size_t)r * (dcols4 * 4) + c4) = o;
}

__global__ __launch_bounds__(256) void k_prep_all(
    const float* __restrict__ dec, const float* __restrict__ ctx,
    const int* __restrict__ y, const float* __restrict__ etab,
    const float* __restrict__ Sw, const float* __restrict__ C0w,
    const float* __restrict__ Vw, const float* __restrict__ Sb,
    const float* __restrict__ Vb, const float* __restrict__ C0b,
    const float* __restrict__ W1, const float* __restrict__ W2w,
    const float* __restrict__ wih0, const float* __restrict__ wih1,
    u16* __restrict__ Xcat, u16* __restrict__ Wcat, float* __restrict__ biasc,
    u16* __restrict__ W1b, u16* __restrict__ W2b,
    u16* __restrict__ wih0b, u16* __restrict__ wih1b)
{
  int bid = blockIdx.x, th = threadIdx.x;
  if (bid < 18750)      prep_main_body(dec, ctx, Xcat, bid * 256 + th);
  else if (bid < 24450) prep_emb_body(y, etab, Xcat, (bid - 18750) * 256 + th);
  else if (bid < 35970) wcat_body(Sw, C0w, Vw, Sb, Vb, C0b, Wcat, biasc, (bid - 24450) * 256 + th);
  else if (bid < 43490) conv_body(W1,   W1b,   24000, 300, 24064, 80, (bid - 35970) * 256 + th);
  else if (bid < 43610) conv_body(W2w,  W2b,   300,   300, 384,   80, (bid - 43490) * 256 + th);
  else if (bid < 43770) conv_body(wih0, wih0b, 400,   300, 512,   80, (bid - 43610) * 256 + th);
  else                  conv_body(wih1, wih1b, 400,   100, 512,   32, (bid - 43770) * 256 + th);
}

// ---------------------------------------------------------------------------
// tlong GEMM with XCD-pinned block remap: the 5 col-blocks of each row-group
// run on the SAME XCD so the A-tile (Xcat rows) is fetched into that L2 once.
// grid = 400 linear (8 XCDs x 10 row-slots x 5 cols), y>=75 exits.
// ---------------------------------------------------------------------------
__global__ __launch_bounds__(256) void k_gemm_tlong(
    const u16* __restrict__ Xcat, const u16* __restrict__ Wcat,
    const float* __restrict__ biasc, u16* __restrict__ tb)
{
  __shared__ u16 As[16384], Bs[16384];
  f32x4 acc[4][4];
  int L = blockIdx.x;
  int xcd = L & 7, s = L >> 3;
  int yy = (s / 5) * 8 + xcd;            // row-group pinned to xcd
  int xx = s % 5;
  if (yy >= 75) return;
  int brow = yy * 128, bcol = xx * 128;
  gemm_core(Xcat, Wcat, 4608, brow, bcol, As, Bs, acc);
  int lane = threadIdx.x & 63, w = threadIdx.x >> 6;
  int wm = w >> 1, wn = w & 1;
  #pragma unroll
  for (int m = 0; m < 4; ++m)
    #pragma unroll
    for (int n = 0; n < 4; ++n)
      #pragma unroll
      for (int r = 0; r < 4; ++r) {
        int row = brow + wm * 64 + m * 16 + ((lane >> 4) << 2) + r;
        int col = bcol + wn * 64 + n * 16 + (lane & 15);
        float v = acc[m][n][r] + biasc[col];
        float o = __shfl_xor(v, 1);
        float t = fmaxf(v, o);
        if ((lane & 1) == 0)
          tb[(size_t)row * 320 + (col >> 1)] = f2b(t);   // maxout pair
      }
}

__global__ __launch_bounds__(256) void k_gemm_a(
    const u16* __restrict__ tb, const u16* __restrict__ W2b,
    const float* __restrict__ W2bias, const float* __restrict__ W1,
    const int* __restrict__ y, u16* __restrict__ ab, u16* __restrict__ qb)
{
  __shared__ u16 As[16384], Bs[16384];
  f32x4 acc[4][4];
  int brow = blockIdx.y * 128, bcol = blockIdx.x * 128;
  gemm_core(tb, W2b, 320, brow, bcol, As, Bs, acc);
  int lane = threadIdx.x & 63, w = threadIdx.x >> 6;
  int wm = w >> 1, wn = w & 1;
  #pragma unroll
  for (int m = 0; m < 4; ++m)
    #pragma unroll
    for (int n = 0; n < 4; ++n)
      #pragma unroll
      for (int r = 0; r < 4; ++r) {
        int row = brow + wm * 64 + m * 16 + ((lane >> 4) << 2) + r;
        int col = bcol + wn * 64 + n * 16 + (lane & 15);
        if (col < 320) {
          float bias = (col < 300) ? W2bias[col] : 0.f;
          float a = acc[m][n][r] + bias;
          ab[(size_t)row * 320 + col] = f2b(a);
          float q = 0.f;
          if (col < 300) {
            int yv = y[row];
            q = a * W1[(size_t)yv * 300 + col];
          }
          qb[(size_t)row * 320 + col] = f2b(q);
        }
      }
}

// ---------------------------------------------------------------------------
// STAGE 1: blocks [0,300) = proj0 (qb @ wih0b -> xp0); [300,14400) = logits
// GEMM writing bf16 lb (coalesced LDS repack) + expf partials.
// ---------------------------------------------------------------------------
__global__ __launch_bounds__(256) void k_s1(
    const u16* __restrict__ ab, const u16* __restrict__ W1b,
    u16* __restrict__ lb, float* __restrict__ part,
    const u16* __restrict__ qb, const u16* __restrict__ wih0b,
    const float* __restrict__ bih0, const float* __restrict__ bhh0,
    float* __restrict__ xp0)
{
  __shared__ u16 smem[32768];                 // 64 KiB GEMM dbuf / repack
  __shared__ float rowsum[128][2];
  f32x4 acc[4][4];
  int bid = blockIdx.x;
  if (bid < 300) {
    int brow = (bid / 4) * 128, bcol = (bid % 4) * 128;
    gemm_core(qb, wih0b, 320, brow, bcol, smem, smem + 16384, acc);
    proj_epilogue(acc, brow, bcol, bih0, bhh0, xp0);
    return;
  }
  int g = bid - 300;
  int brow = (g / NCB) * 128, bcol = (g % NCB) * 128;
  gemm_core(ab, W1b, 320, brow, bcol, smem, smem + 16384, acc);
  int lane = threadIdx.x & 63, w = threadIdx.x >> 6;
  int wm = w >> 1, wn = w & 1;
  #pragma unroll
  for (int m = 0; m < 4; ++m)
    #pragma unroll
    for (int r = 0; r < 4; ++r) {
      int lrow = wm * 64 + m * 16 + ((lane >> 4) << 2) + r;
      float es = 0.f;
      #pragma unroll
      for (int n = 0; n < 4; ++n) {
        int lcol = wn * 64 + n * 16 + (lane & 15);
        float v = acc[m][n][r];
        smem[lrow * 136 + lcol] = f2b(v);     // [128][136] u16, +8 pad
        if (bcol + lcol < VOCAB) es += __expf(v);
      }
      es += __shfl_xor(es, 1); es += __shfl_xor(es, 2);
      es += __shfl_xor(es, 4); es += __shfl_xor(es, 8);
      if ((lane & 15) == 0) rowsum[lrow][wn] = es;
    }
  __syncthreads();
  if (threadIdx.x < 128)
    part[(size_t)(brow + threadIdx.x) * NCB + (g % NCB)] =
        rowsum[threadIdx.x][0] + rowsum[threadIdx.x][1];
  #pragma unroll
  for (int j = 0; j < 8; ++j) {
    int ch   = j * 256 + threadIdx.x;
    int rowl = ch >> 4;
    int c16  = (ch & 15) << 3;
    u16x8 v = *(const u16x8*)(smem + rowl * 136 + c16);
    *(u16x8*)(lb + (size_t)(brow + rowl) * 24064 + bcol + c16) = v;
  }
}

// ---------------------------------------------------------------------------
// LSTM bodies (512 threads)
// ---------------------------------------------------------------------------
__device__ __forceinline__ void lstm0_body(
    const float* __restrict__ xp0, const float* __restrict__ whh0,
    u16* __restrict__ h0b, int b)
{
  int g = threadIdx.x;
  __shared__ float h[100];
  __shared__ float act[400];
  float wrow[100];
  if (g < 400) {
    const float4* wr = (const float4*)(whh0 + (size_t)g * 100);
    #pragma unroll
    for (int q = 0; q < 25; ++q) {
      float4 t = wr[q];
      wrow[4 * q] = t.x; wrow[4 * q + 1] = t.y; wrow[4 * q + 2] = t.z; wrow[4 * q + 3] = t.w;
    }
  }
  if (g < 100) h[g] = 0.f;
  float c = 0.f;
  __syncthreads();
  for (int t = 0; t < 50; ++t) {
    if (g < 400) {
      float s = xp0[(size_t)(b * 50 + t) * 400 + g];
      const float4* hv = (const float4*)h;
      #pragma unroll
      for (int q = 0; q < 25; ++q) {
        float4 hh = hv[q];
        s += wrow[4 * q] * hh.x + wrow[4 * q + 1] * hh.y
           + wrow[4 * q + 2] * hh.z + wrow[4 * q + 3] * hh.w;
      }
      act[g] = (g >= 200 && g < 300) ? tanhf(s) : 1.f / (1.f + __expf(-s));
    }
    __syncthreads();
    if (g < 100) {
      c = act[100 + g] * c + act[g] * act[200 + g];
      float hn = act[300 + g] * tanhf(c);
      h[g] = hn;
      h0b[(size_t)(b * 50 + t) * 128 + g] = f2b(hn);
    } else if (g < 128) {
      h0b[(size_t)(b * 50 + t) * 128 + g] = 0;
    }
    __syncthreads();
  }
}

__device__ __forceinline__ void lstm1_body(
    const float* __restrict__ xp1, const float* __restrict__ whh1,
    const int* __restrict__ y, const float* __restrict__ wqe,
    const float* __restrict__ wqeb, float* __restrict__ qout, int b)
{
  int g = threadIdx.x;
  __shared__ float h[100];
  __shared__ float act[400];
  __shared__ float hsel[100];
  __shared__ int idx1;
  float wrow[100];
  if (g < 400) {
    const float4* wr = (const float4*)(whh1 + (size_t)g * 100);
    #pragma unroll
    for (int q = 0; q < 25; ++q) {
      float4 t = wr[q];
      wrow[4 * q] = t.x; wrow[4 * q + 1] = t.y; wrow[4 * q + 2] = t.z; wrow[4 * q + 3] = t.w;
    }
  }
  if (g == 0) {
    int ix = 49;
    for (int t = 0; t < 50; ++t) { if (y[b * 50 + t] == 0) { ix = t; break; } }
    idx1 = ix;
  }
  if (g < 100) { h[g] = 0.f; hsel[g] = 0.f; }
  float c = 0.f;
  __syncthreads();
  for (int t = 0; t < 50; ++t) {
    if (g < 400) {
      float s = xp1[(size_t)(b * 50 + t) * 400 + g];
      const float4* hv = (const float4*)h;
      #pragma unroll
      for (int q = 0; q < 25; ++q) {
        float4 hh = hv[q];
        s += wrow[4 * q] * hh.x + wrow[4 * q + 1] * hh.y
           + wrow[4 * q + 2] * hh.z + wrow[4 * q + 3] * hh.w;
      }
      act[g] = (g >= 200 && g < 300) ? tanhf(s) : 1.f / (1.f + __expf(-s));
    }
    __syncthreads();
    if (g < 100) {
      c = act[100 + g] * c + act[g] * act[200 + g];
      float hn = act[300 + g] * tanhf(c);
      h[g] = hn;
      if (t == idx1) hsel[g] = hn;
    }
    __syncthreads();
  }
  if (g == 0) {
    float s = wqeb[0];
    for (int j = 0; j < 100; ++j) s += hsel[j] * wqe[j];
    qout[b] = 1.f / (1.f + __expf(-s));
  }
}

// fixup body: rows [r0, r0+nrows) of lb -> d_out, grid-stride over nb blocks
__device__ __forceinline__ void fixup_body(
    const u16* __restrict__ lb, const float* __restrict__ logl,
    float* __restrict__ out, int r0, int nrows, int bid, int nb, int nthreads)
{
  size_t i = (size_t)bid * nthreads + threadIdx.x;
  size_t stride = (size_t)nb * nthreads;
  const size_t total = (size_t)nrows * (VOCAB / 8);
  for (; i < total; i += stride) {
    size_t rowl = i / (VOCAB / 8);
    int c8 = (int)(i % (VOCAB / 8)) * 8;
    size_t row = r0 + rowl;
    float l = logl[row];
    u16x8 v = *(const u16x8*)(lb + row * 24064 + c8);
    float4 o0, o1;
    o0.x = b2f(v[0]) - l; o0.y = b2f(v[1]) - l; o0.z = b2f(v[2]) - l; o0.w = b2f(v[3]) - l;
    o1.x = b2f(v[4]) - l; o1.y = b2f(v[5]) - l; o1.z = b2f(v[6]) - l; o1.w = b2f(v[7]) - l;
    float* op = out + row * VOCAB + c8;
    *(float4*)op = o0;
    *(float4*)(op + 4) = o1;
  }
}

// ---------------------------------------------------------------------------
// STAGE 2 (512t): blocks [0,1200) rowlog (8 rows each); [1200,1392) lstm0
// ---------------------------------------------------------------------------
__global__ __launch_bounds__(512) void k_s2(
    const float* __restrict__ part, float* __restrict__ logl,
    const float* __restrict__ xp0, const float* __restrict__ whh0,
    u16* __restrict__ h0b)
{
  int bid = blockIdx.x;
  if (bid < 1200) {
    int row = bid * 8 + (threadIdx.x >> 6);
    int l = threadIdx.x & 63;
    const float* p = part + (size_t)row * NCB;
    float s = p[l] + p[l + 64] + (l < 60 ? p[l + 128] : 0.f);
    s += __shfl_xor(s, 1);  s += __shfl_xor(s, 2);  s += __shfl_xor(s, 4);
    s += __shfl_xor(s, 8);  s += __shfl_xor(s, 16); s += __shfl_xor(s, 32);
    if (l == 0) logl[row] = logf(s);
    return;
  }
  lstm0_body(xp0, whh0, h0b, bid - 1200);
}

// ---------------------------------------------------------------------------
// STAGE 3 (256t): blocks [0,3072) fixup rows [0,6400); [3072,3372) proj1
// ---------------------------------------------------------------------------
__global__ __launch_bounds__(256) void k_s3(
    const u16* __restrict__ lb, const float* __restrict__ logl,
    float* __restrict__ out,
    const u16* __restrict__ h0b, const u16* __restrict__ wih1b,
    const float* __restrict__ bih1, const float* __restrict__ bhh1,
    float* __restrict__ xp1)
{
  int bid = blockIdx.x;
  if (bid < 3072) {
    fixup_body(lb, logl, out, 0, 6400, bid, 3072, 256);
    return;
  }
  __shared__ u16 As[16384], Bs[16384];
  f32x4 acc[4][4];
  int pb = bid - 3072;
  int brow = (pb / 4) * 128, bcol = (pb % 4) * 128;
  gemm_core(h0b, wih1b, 128, brow, bcol, As, Bs, acc);
  proj_epilogue(acc, brow, bcol, bih1, bhh1, xp1);
}

// ---------------------------------------------------------------------------
// STAGE 4 (512t): blocks [0,192) lstm1; [192,1216) fixup rows [6400,9600)
// ---------------------------------------------------------------------------
__global__ __launch_bounds__(512) void k_s4(
    const u16* __restrict__ lb, const float* __restrict__ logl,
    float* __restrict__ out,
    const float* __restrict__ xp1, const float* __restrict__ whh1,
    const int* __restrict__ y, const float* __restrict__ wqe,
    const float* __restrict__ wqeb, float* __restrict__ qout)
{
  int bid = blockIdx.x;
  if (bid < 192) {
    lstm1_body(xp1, whh1, y, wqe, wqeb, qout, bid);
    return;
  }
  fixup_body(lb, logl, out, 6400, 3200, bid - 192, 1024, 512);
}

// ---------------------------------------------------------------------------
// fp32 fallback kernels (only if ws too small for lb)
// ---------------------------------------------------------------------------
__global__ __launch_bounds__(256) void k_gemm_logits_f32(
    const u16* __restrict__ ab, const u16* __restrict__ W1b,
    float* __restrict__ dout, float* __restrict__ part)
{
  __shared__ u16 As[16384], Bs[16384];
  __shared__ float rowsum[128][2];
  f32x4 acc[4][4];
  int brow = blockIdx.y * 128, bcol = blockIdx.x * 128;
  gemm_core(ab, W1b, 320, brow, bcol, As, Bs, acc);
  int lane = threadIdx.x & 63, w = threadIdx.x >> 6;
  int wm = w >> 1, wn = w & 1;
  #pragma unroll
  for (int m = 0; m < 4; ++m)
    #pragma unroll
    for (int r = 0; r < 4; ++r) {
      int lrow = wm * 64 + m * 16 + ((lane >> 4) << 2) + r;
      size_t grow = (size_t)(brow + lrow);
      float es = 0.f;
      #pragma unroll
      for (int n = 0; n < 4; ++n) {
        int col = bcol + wn * 64 + n * 16 + (lane & 15);
        float v = acc[m][n][r];
        if (col < VOCAB) { dout[grow * VOCAB + col] = v; es += __expf(v); }
      }
      es += __shfl_xor(es, 1); es += __shfl_xor(es, 2);
      es += __shfl_xor(es, 4); es += __shfl_xor(es, 8);
      if ((lane & 15) == 0) rowsum[lrow][wn] = es;
    }
  __syncthreads();
  if (threadIdx.x < 128)
    part[(size_t)(brow + threadIdx.x) * NCB + blockIdx.x] =
        rowsum[threadIdx.x][0] + rowsum[threadIdx.x][1];
}

__global__ __launch_bounds__(256) void k_gemm_proj(
    const u16* __restrict__ Ab, const u16* __restrict__ Bb, int K,
    const float* __restrict__ b1, const float* __restrict__ b2, float* __restrict__ out)
{
  __shared__ u16 As[16384], Bs[16384];
  f32x4 acc[4][4];
  int brow = blockIdx.y * 128, bcol = blockIdx.x * 128;
  gemm_core(Ab, Bb, K, brow, bcol, As, Bs, acc);
  proj_epilogue(acc, brow, bcol, b1, b2, out);
}

__global__ __launch_bounds__(256) void k_rowlog256(
    const float* __restrict__ part, float* __restrict__ logl)
{
  int row = blockIdx.x * 4 + (threadIdx.x >> 6);
  int l = threadIdx.x & 63;
  const float* p = part + (size_t)row * NCB;
  float s = p[l] + p[l + 64] + (l < 60 ? p[l + 128] : 0.f);
  s += __shfl_xor(s, 1);  s += __shfl_xor(s, 2);  s += __shfl_xor(s, 4);
  s += __shfl_xor(s, 8);  s += __shfl_xor(s, 16); s += __shfl_xor(s, 32);
  if (l == 0) logl[row] = logf(s);
}

__global__ __launch_bounds__(256) void k_fixup_f32(
    float4* __restrict__ out4, const float* __restrict__ logl)
{
  size_t i = (size_t)blockIdx.x * blockDim.x + threadIdx.x;
  size_t stride = (size_t)gridDim.x * blockDim.x;
  const size_t total = (size_t)BT * (VOCAB / 4);
  for (; i < total; i += stride) {
    size_t row = i / (VOCAB / 4);
    float l = logl[row];
    float4 v = out4[i];
    v.x -= l; v.y -= l; v.z -= l; v.w -= l;
    out4[i] = v;
  }
}

__global__ __launch_bounds__(512) void k_lstm0(
    const float* __restrict__ xp0, const float* __restrict__ whh0, u16* __restrict__ h0b)
{ lstm0_body(xp0, whh0, h0b, blockIdx.x); }

__global__ __launch_bounds__(512) void k_lstm1(
    const float* __restrict__ xp1, const float* __restrict__ whh1,
    const int* __restrict__ y, const float* __restrict__ wqe,
    const float* __restrict__ wqeb, float* __restrict__ qout)
{ lstm1_body(xp1, whh1, y, wqe, wqeb, qout, blockIdx.x); }

// ---------------------------------------------------------------------------
extern "C" void kernel_launch(void* const* d_in, const int* in_sizes, int n_in,
                              void* d_out, int out_size, void* d_ws, size_t ws_size,
                              hipStream_t stream) {
  const float* dec  = (const float*)d_in[0];
  const int*   y    = (const int*)d_in[1];
  const float* ctx  = (const float*)d_in[2];
  const float* etab = (const float*)d_in[3];
  const float* W1   = (const float*)d_in[4];
  const float* Sw   = (const float*)d_in[5];
  const float* Sb   = (const float*)d_in[6];
  const float* Vw   = (const float*)d_in[7];
  const float* Vb   = (const float*)d_in[8];
  const float* C0w  = (const float*)d_in[9];
  const float* C0b  = (const float*)d_in[10];
  const float* W2w  = (const float*)d_in[11];
  const float* W2bias = (const float*)d_in[12];
  const float* wih0 = (const float*)d_in[13];
  const float* whh0 = (const float*)d_in[14];
  const float* bih0 = (const float*)d_in[15];
  const float* bhh0 = (const float*)d_in[16];
  const float* wih1 = (const float*)d_in[17];
  const float* whh1 = (const float*)d_in[18];
  const float* bih1 = (const float*)d_in[19];
  const float* bhh1 = (const float*)d_in[20];
  const float* wqe  = (const float*)d_in[21];
  const float* wqeb = (const float*)d_in[22];

  char* ws = (char*)d_ws;
  u16*   Xcat  = (u16*)(ws + 0);            // 9600x4608 bf16 = 88,473,600
  u16*   Wcat  = (u16*)(ws + 88473600);     // 640x4608 bf16  =  5,898,240
  float* biasc = (float*)(ws + 94371840);   // 640 f32
  u16*   tb    = (u16*)(ws + 94374400);     // 9600x320 bf16
  u16*   W2b   = (u16*)(ws + 100518400);    // 384x320 bf16
  u16*   ab    = (u16*)(ws + 100764160);    // 9600x320 bf16
  u16*   qb    = (u16*)(ws + 106908160);    // 9600x320 bf16
  u16*   W1b   = (u16*)(ws + 113052160);    // 24064x320 bf16
  float* part  = (float*)(ws + 128453120);  // 9600x188 f32
  float* logl  = (float*)(ws + 135672320);  // 9600 f32
  u16*   wih0b = (u16*)(ws + 135710720);    // 512x320 bf16
  float* xp0   = (float*)(ws + 136038400);  // 9600x400 f32
  u16*   h0b   = (u16*)(ws + 151398400);    // 9600x128 bf16
  u16*   wih1b = (u16*)(ws + 153856000);    // 512x128 bf16
  float* xp1   = (float*)(ws + 153987072);  // 9600x400 f32  (end 169,347,072)
  u16*   lb    = (u16*)(ws + 169347072);    // 9600x24064 bf16 = 462,028,800
  const size_t WS_NEED_BF16 = 169347072ull + 462028800ull;   // 631,375,872
  const bool use_bf16_logits = (ws_size >= WS_NEED_BF16);

  float* bout  = (float*)d_out;
  float* qeout = bout + (size_t)BT * VOCAB;

  k_prep_all<<<43834, 256, 0, stream>>>(dec, ctx, y, etab, Sw, C0w, Vw, Sb, Vb, C0b,
                                        W1, W2w, wih0, wih1,
                                        Xcat, Wcat, biasc, W1b, W2b, wih0b, wih1b);

  k_gemm_tlong<<<400, 256, 0, stream>>>(Xcat, Wcat, biasc, tb);
  k_gemm_a<<<dim3(3, 75), 256, 0, stream>>>(tb, W2b, W2bias, W1, y, ab, qb);

  if (use_bf16_logits) {
    k_s1<<<14400, 256, 0, stream>>>(ab, W1b, lb, part, qb, wih0b, bih0, bhh0, xp0);
    k_s2<<<1392, 512, 0, stream>>>(part, logl, xp0, whh0, h0b);
    k_s3<<<3372, 256, 0, stream>>>(lb, logl, bout, h0b, wih1b, bih1, bhh1, xp1);
    k_s4<<<1216, 512, 0, stream>>>(lb, logl, bout, xp1, whh1, y, wqe, wqeb, qeout);
  } else {
    k_gemm_logits_f32<<<dim3(NCB, 75), 256, 0, stream>>>(ab, W1b, bout, part);
    k_rowlog256<<<2400, 256, 0, stream>>>(part, logl);
    k_fixup_f32<<<4096, 256, 0, stream>>>((float4*)bout, logl);
    k_gemm_proj<<<dim3(4, 75), 256, 0, stream>>>(qb, wih0b, 320, bih0, bhh0, xp0);
    k_lstm0<<<192, 512, 0, stream>>>(xp0, whh0, h0b);
    k_gemm_proj<<<dim3(4, 75), 256, 0, stream>>>(h0b, wih1b, 128, bih1, bhh1, xp1);
    k_lstm1<<<192, 512, 0, stream>>>(xp1, whh1, y, wqe, wqeb, qeout);
  }
}